// Round 1
// baseline (2660.203 us; speedup 1.0000x reference)
//
#include <hip/hip_runtime.h>

// SIR forward roll: B independent rows, each a sequential scan over H steps.
// Memory-bound: ~0.4 GB read, ~0.94 GB write -> ~215 us floor at 6.3 TB/s.
// One thread per row; time chunked by TCH=16 so each thread's loads/stores
// cover full 64B sectors back-to-back (rows are 1KB apart -> no wave-level
// coalescing possible with this layout; sector-granular is the best case).

constexpr float EPS_C        = 1e-8f;
constexpr float RESID_CLIP_C = 10000.0f;
constexpr int   TCH          = 16;   // time steps per chunk (64B per output)

__global__ __launch_bounds__(256, 2) void sir_roll_kernel(
    const float* __restrict__ beta_t,
    const float* __restrict__ gamma_t,
    const float* __restrict__ mort_t,
    const float* __restrict__ S0v,
    const float* __restrict__ I0v,
    const float* __restrict__ R0v,
    const float* __restrict__ popv,
    float* __restrict__ out,
    int B, int H)
{
    const int b = blockIdx.x * blockDim.x + threadIdx.x;
    if (b >= B) return;

    const int    HP1   = H + 1;
    const size_t trajN = (size_t)B * (size_t)HP1;
    const size_t rateN = (size_t)B * (size_t)H;

    // Output blocks, concatenated flat in reference return order.
    float* __restrict__ Straj  = out + (size_t)b * HP1;           // [B,H+1]
    float* __restrict__ Itraj  = Straj + trajN;
    float* __restrict__ Rtraj  = Straj + 2 * trajN;
    float* __restrict__ Dtraj  = Straj + 3 * trajN;
    float* __restrict__ deathO = out + 4 * trajN + (size_t)b * H; // [B,H]
    float* __restrict__ residO = deathO + rateN;
    float* __restrict__ betaO  = deathO + 2 * rateN;

    const float* __restrict__ betaI  = beta_t  + (size_t)b * H;
    const float* __restrict__ gammaI = gamma_t + (size_t)b * H;
    const float* __restrict__ mortI  = mort_t  + (size_t)b * H;

    const float pop = popv[b];
    float S = S0v[b], I = I0v[b], R = R0v[b];
    // _sanitize_initial_states: renormalize to population
    const float scale0 = pop / (S + I + R + EPS_C);
    S *= scale0; I *= scale0; R *= scale0;
    float D = 0.0f;
    const float inv_pop = 1.0f / pop;

    Straj[0] = S; Itraj[0] = I; Rtraj[0] = R; Dtraj[0] = 0.0f;

    for (int t0 = 0; t0 < H; t0 += TCH) {
        // Stage rate chunk: 3 x 64B of aligned float4 loads (row base b*H is
        // 1KB aligned, t0 multiple of 16).
        float4 bv[TCH / 4], gv[TCH / 4], mv[TCH / 4];
        #pragma unroll
        for (int k = 0; k < TCH / 4; ++k) {
            bv[k] = reinterpret_cast<const float4*>(betaI  + t0)[k];
            gv[k] = reinterpret_cast<const float4*>(gammaI + t0)[k];
            mv[k] = reinterpret_cast<const float4*>(mortI  + t0)[k];
        }

        float oS[TCH], oI[TCH], oR[TCH], oD[TCH], oDe[TCH], oRe[TCH];
        #pragma unroll
        for (int j = 0; j < TCH; ++j) {
            const float beta  = reinterpret_cast<const float*>(bv)[j];
            const float gamma = reinterpret_cast<const float*>(gv)[j];
            const float mu    = reinterpret_cast<const float*>(mv)[j];

            const float bsi = beta * S * I * inv_pop;   // beta*S*I/N
            const float rec = gamma * I;
            const float dth = mu * I;

            float S1 = fmaxf(S - bsi, 0.0f);            // dt = 1
            float I1 = fmaxf(I + (bsi - rec - dth), 0.0f);
            float R1 = fmaxf(R + rec, 0.0f);
            float D1 = fmaxf(D + dth, 0.0f);

            const float sc = pop / (S1 + I1 + R1 + D1 + EPS_C); // mass conservation
            S1 *= sc;
            const float In = I1 * sc;
            R1 *= sc;
            D1 *= sc;

            const float dI_exp = bsi - rec - dth;
            const float dI_act = In - I;                // dt = 1
            const float rr     = dI_act - dI_exp;
            const float res    = fminf(rr * rr, RESID_CLIP_C);

            S = S1; I = In; R = R1; D = D1;
            oS[j] = S; oI[j] = I; oR[j] = R; oD[j] = D;
            oDe[j] = dth; oRe[j] = res;
        }

        // Trajectory rows start at b*(H+1)+1 -> 4B aligned only: scalar
        // stores, but 16 consecutive addresses back-to-back fill the 64B
        // sector quickly (minimizes partial-line eviction pressure on L2).
        #pragma unroll
        for (int j = 0; j < TCH; ++j) {
            Straj[t0 + 1 + j] = oS[j];
            Itraj[t0 + 1 + j] = oI[j];
            Rtraj[t0 + 1 + j] = oR[j];
            Dtraj[t0 + 1 + j] = oD[j];
        }
        // death / residual / beta-copy rows are 16B aligned -> float4 stores.
        #pragma unroll
        for (int k = 0; k < TCH / 4; ++k) {
            reinterpret_cast<float4*>(deathO + t0)[k] =
                make_float4(oDe[4*k], oDe[4*k+1], oDe[4*k+2], oDe[4*k+3]);
            reinterpret_cast<float4*>(residO + t0)[k] =
                make_float4(oRe[4*k], oRe[4*k+1], oRe[4*k+2], oRe[4*k+3]);
            reinterpret_cast<float4*>(betaO + t0)[k] = bv[k];
        }
    }
}

extern "C" void kernel_launch(void* const* d_in, const int* in_sizes, int n_in,
                              void* d_out, int out_size, void* d_ws, size_t ws_size,
                              hipStream_t stream) {
    const float* beta  = (const float*)d_in[0];
    const float* gamma = (const float*)d_in[1];
    const float* mort  = (const float*)d_in[2];
    const float* S0    = (const float*)d_in[3];
    const float* I0    = (const float*)d_in[4];
    const float* R0    = (const float*)d_in[5];
    const float* pop   = (const float*)d_in[6];

    const int B = in_sizes[3];            // 131072
    const int H = in_sizes[0] / B;        // 256

    dim3 block(256);
    dim3 grid((B + 255) / 256);           // 512 blocks
    hipLaunchKernelGGL(sir_roll_kernel, grid, block, 0, stream,
                       beta, gamma, mort, S0, I0, R0, pop,
                       (float*)d_out, B, H);
}